// Round 4
// baseline (5127.140 us; speedup 1.0000x reference)
//
#include <hip/hip_runtime.h>
#include <math.h>

#define NFULL 2177   // 1 + L + S
#define NN    2176   // minor size = 17*128
#define NMAT  8      // 4 batches x {z, target}
#define NBATCH 4
#define LDST  68     // LDS row stride for 64x64 tiles (float4-aligned, odd/4 banks)
#define ATILES 68    // 32-row tiles per matrix dim
#define FRAGM ((size_t)ATILES * 8 * 512)  // shorts per matrix per plane

typedef unsigned int  u32;
typedef unsigned short u16;
typedef __attribute__((ext_vector_type(8)))  short short8;
typedef __attribute__((ext_vector_type(16))) float f32x16;

__device__ inline void bf16split(float x, u16& hi, u16& lo) {
  u32 xb = __float_as_uint(x);
  u32 h = (xb + 0x7FFFu + ((xb >> 16) & 1u)) >> 16;
  float r = x - __uint_as_float(h << 16);
  u32 rb = __float_as_uint(r);
  u32 l = (rb + 0x7FFFu + ((rb >> 16) & 1u)) >> 16;
  hi = (u16)h; lo = (u16)l;
}

__device__ inline void packstore(short* P, size_t off, const u16 v[8]) {
  *(uint4*)(P + off) = make_uint4(v[0] | ((u32)v[1] << 16), v[2] | ((u32)v[3] << 16),
                                  v[4] | ((u32)v[5] << 16), v[6] | ((u32)v[7] << 16));
}

// one fragment chunk (hi+lo planes) from LDS tile X (stride LDST)
__device__ inline void frag_from_lds(const float* X, int locbase, int kl, int l,
                                     short* Phi, short* Plo, size_t off) {
  const float* p = &X[(locbase + (l & 31)) * LDST + kl];
  float4 v0 = *(const float4*)&p[0];
  float4 v1 = *(const float4*)&p[4];
  u16 hi[8], lo[8];
  bf16split(v0.x, hi[0], lo[0]); bf16split(v0.y, hi[1], lo[1]);
  bf16split(v0.z, hi[2], lo[2]); bf16split(v0.w, hi[3], lo[3]);
  bf16split(v1.x, hi[4], lo[4]); bf16split(v1.y, hi[5], lo[5]);
  bf16split(v1.z, hi[6], lo[6]); bf16split(v1.w, hi[7], lo[7]);
  packstore(Phi, off, hi);
  packstore(Plo, off, lo);
}

__device__ inline void load64(float* X, const float* A, int r0, int c0, int tid) {
#pragma unroll
  for (int it = 0; it < 4; ++it) {
    int f = tid + it * 256;
    int r = f >> 4, c4 = f & 15;
    *(float4*)&X[r * LDST + c4 * 4] = *(const float4*)&A[(size_t)(r0 + r) * NN + c0 + c4 * 4];
  }
}
__device__ inline void store64(const float* X, float* A, int r0, int c0, int tid) {
#pragma unroll
  for (int it = 0; it < 4; ++it) {
    int f = tid + it * 256;
    int r = f >> 4, c4 = f & 15;
    *(float4*)&A[(size_t)(r0 + r) * NN + c0 + c4 * 4] = *(const float4*)&X[r * LDST + c4 * 4];
  }
}

// in-place LU of 64x64 LDS tile (L unit-lower \ U upper), 256 threads
__device__ inline void factor64(float* D, int tid) {
  for (int j = 0; j < 63; ++j) {
    float inv = 1.0f / D[j * LDST + j];
    for (int r = j + 1 + tid; r < 64; r += 256) D[r * LDST + j] *= inv;
    __syncthreads();
    int cc = j + 1 + (tid & 63);
    for (int rr = j + 1 + (tid >> 6); rr < 64; rr += 4)
      if (cc < 64) D[rr * LDST + cc] -= D[rr * LDST + j] * D[j * LDST + cc];
    __syncthreads();
  }
}

// V = inv(upper(S)) dense 64x64 (zeros below), 2-level 32-block method
__device__ inline void inv_upper64(const float* S, float* V, float* scr, int tid) {
  if (tid < 64) {
    int o = (tid >> 5) * 32, j = tid & 31;
    V[(o + j) * LDST + o + j] = 1.0f / S[(o + j) * LDST + o + j];
    for (int i = j - 1; i >= 0; --i) {
      float a = 0.f;
      for (int t = i + 1; t <= j; ++t) a += S[(o + i) * LDST + o + t] * V[(o + t) * LDST + o + j];
      V[(o + i) * LDST + o + j] = -a / S[(o + i) * LDST + o + i];
    }
    for (int i = j + 1; i < 32; ++i) V[(o + i) * LDST + o + j] = 0.f;
  }
  for (int e = tid; e < 1024; e += 256) V[(32 + (e >> 5)) * LDST + (e & 31)] = 0.f;
  __syncthreads();
  for (int e = tid; e < 1024; e += 256) {            // scr = B * invC
    int a = e >> 5, c = e & 31; float s = 0.f;
    for (int t = 0; t < 32; ++t) s += S[a * LDST + 32 + t] * V[(32 + t) * LDST + 32 + c];
    scr[a * 33 + c] = s;
  }
  __syncthreads();
  for (int e = tid; e < 1024; e += 256) {            // V01 = -invA * scr
    int a = e >> 5, c = e & 31; float s = 0.f;
    for (int t = 0; t < 32; ++t) s += V[a * LDST + t] * scr[t * 33 + c];
    V[a * LDST + 32 + c] = -s;
  }
  __syncthreads();
}

// V = inv(unit_lower(S)) dense 64x64 (unit diag, zeros above)
__device__ inline void inv_lower64(const float* S, float* V, float* scr, int tid) {
  if (tid < 64) {
    int o = (tid >> 5) * 32, j = tid & 31;
    V[(o + j) * LDST + o + j] = 1.0f;
    for (int i = j + 1; i < 32; ++i) {
      float a = 0.f;
      for (int t = j; t < i; ++t) a += S[(o + i) * LDST + o + t] * V[(o + t) * LDST + o + j];
      V[(o + i) * LDST + o + j] = -a;
    }
    for (int i = 0; i < j; ++i) V[(o + i) * LDST + o + j] = 0.f;
  }
  for (int e = tid; e < 1024; e += 256) V[(e >> 5) * LDST + 32 + (e & 31)] = 0.f;
  __syncthreads();
  for (int e = tid; e < 1024; e += 256) {            // scr = S10 * invA
    int a = e >> 5, c = e & 31; float s = 0.f;
    for (int t = 0; t < 32; ++t) s += S[(32 + a) * LDST + t] * V[t * LDST + c];
    scr[a * 33 + c] = s;
  }
  __syncthreads();
  for (int e = tid; e < 1024; e += 256) {            // V10 = -invC * scr
    int a = e >> 5, c = e & 31; float s = 0.f;
    for (int t = 0; t < 32; ++t) s += V[(32 + a) * LDST + 32 + t] * scr[t * 33 + c];
    V[(32 + a) * LDST + c] = -s;
  }
  __syncthreads();
}

// acc = P(64x64) * Q(64x64), 4x4 microtile per thread
__device__ inline void gemm64(const float* P, const float* Q, float acc[4][4], int r0, int c0) {
#pragma unroll
  for (int i = 0; i < 4; ++i)
#pragma unroll
    for (int j = 0; j < 4; ++j) acc[i][j] = 0.f;
  for (int kk = 0; kk < 64; kk += 4) {
    float4 p[4], q[4];
#pragma unroll
    for (int i = 0; i < 4; ++i) p[i] = *(const float4*)&P[(r0 + i) * LDST + kk];
#pragma unroll
    for (int t = 0; t < 4; ++t) q[t] = *(const float4*)&Q[(kk + t) * LDST + c0];
#pragma unroll
    for (int t = 0; t < 4; ++t) {
      float4 qt = q[t];
#pragma unroll
      for (int i = 0; i < 4; ++i) {
        float pv = ((const float*)&p[i])[t];
        acc[i][0] += pv * qt.x; acc[i][1] += pv * qt.y;
        acc[i][2] += pv * qt.z; acc[i][3] += pv * qt.w;
      }
    }
  }
}

// acc[i][j] = sum_k P[r0+i][k] * Q[c0+j][k]   (Q stored transposed)
__device__ inline void gemm64_bt(const float* P, const float* Q, float acc[4][4], int r0, int c0) {
#pragma unroll
  for (int i = 0; i < 4; ++i)
#pragma unroll
    for (int j = 0; j < 4; ++j) acc[i][j] = 0.f;
  for (int kk = 0; kk < 64; kk += 4) {
    float4 p[4], q[4];
#pragma unroll
    for (int i = 0; i < 4; ++i) p[i] = *(const float4*)&P[(r0 + i) * LDST + kk];
#pragma unroll
    for (int j = 0; j < 4; ++j) q[j] = *(const float4*)&Q[(c0 + j) * LDST + kk];
#pragma unroll
    for (int t = 0; t < 4; ++t)
#pragma unroll
      for (int i = 0; i < 4; ++i) {
        float pv = ((const float*)&p[i])[t];
#pragma unroll
        for (int j = 0; j < 4; ++j) acc[i][j] += pv * ((const float*)&q[j])[t];
      }
  }
}

__device__ inline void rmw_tile(float* __restrict__ A, int R0, int C0, const f32x16& ac) {
#pragma unroll
  for (int reg = 0; reg < 16; ++reg) {
    int row = R0 + (reg & 3) + 8 * (reg >> 2);
    A[(size_t)row * NN + C0] -= ac[reg];
  }
}

// ---------------- build phase ----------------

__global__ void init_cs_kernel(float* __restrict__ cs) {
  int i = blockIdx.x * blockDim.x + threadIdx.x;
  if (i < NMAT * NN) cs[i] = 0.f;
}

__global__ __launch_bounds__(256) void build_kernel(
    const float* __restrict__ scores, const float* __restrict__ zm,
    const float* __restrict__ tm, const int* __restrict__ lengths,
    float* __restrict__ M, float* __restrict__ cs) {
  int c = blockIdx.x * 256 + threadIdx.x;
  if (c >= NN) return;
  int b = blockIdx.z;
  int len = lengths[b];
  int j = c + 1;
  bool jv = (j < len);
  int r0 = blockIdx.y * 16;
  size_t sbase = (size_t)b * NFULL * NFULL;
  float* Mz = M + (size_t)b * NN * NN;
  float* Mt = M + (size_t)(NBATCH + b) * NN * NN;
  float az = 0.f, at = 0.f;
  for (int rr = 0; rr < 16; ++rr) {
    int r = r0 + rr, i = r + 1;
    float vz = 0.f, vt = 0.f;
    if (jv && i < len) {
      size_t off = sbase + (size_t)i * NFULL + j;
      float e = __expf(scores[off]);
      vz = e * zm[off];
      vt = e * tm[off];
    }
    Mz[(size_t)r * NN + c] = -vz;
    Mt[(size_t)r * NN + c] = -vt;
    az += vz; at += vt;
  }
  atomicAdd(&cs[b * NN + c], az);
  atomicAdd(&cs[(NBATCH + b) * NN + c], at);
}

__global__ void diag_fix_kernel(const float* __restrict__ scores,
                                const float* __restrict__ zm,
                                const float* __restrict__ tm,
                                const int* __restrict__ lengths,
                                const float* __restrict__ cs,
                                float* __restrict__ M) {
  int c = blockIdx.x * 256 + threadIdx.x;
  if (c >= NN) return;
  int m = blockIdx.y;
  int b = m & 3;
  const float* msk = (m < NBATCH) ? zm : tm;
  int len = lengths[b];
  int j = c + 1;
  float w0 = 0.f, pad = 1.f;
  if (j < len) {
    size_t off = (size_t)b * NFULL * NFULL + j;
    w0 = __expf(scores[off]) * msk[off];
    pad = 0.f;
  }
  M[(size_t)m * NN * NN + (size_t)c * NN + c] = cs[m * NN + c] + w0 + pad;
}

// ---------------- panel kernels ----------------

// L-solve via inverse: T(64xrows) x invU(D_slab); writes fp32 + A-frags s=slab*4..+4
__device__ void psolve_body(float* __restrict__ M, short* __restrict__ Ahi,
                            short* __restrict__ Alo, int k0, int slab, int bx,
                            int m, int tid, float* X, float* Y, float* scr) {
  float* A = M + (size_t)m * NN * NN;
  int d0 = k0 + 64 * slab;
  int gr0 = k0 + 64 * (slab + 1) + bx * 64;
  load64(X, A, d0, d0, tid);
  __syncthreads();
  inv_upper64(X, Y, scr, tid);
  load64(X, A, gr0, d0, tid);
  __syncthreads();
  int r0 = (tid >> 4) * 4, c0 = (tid & 15) * 4;
  float acc[4][4];
  gemm64(X, Y, acc, r0, c0);
  __syncthreads();
#pragma unroll
  for (int i = 0; i < 4; ++i) {
    *(float4*)&A[(size_t)(gr0 + r0 + i) * NN + d0 + c0] =
        make_float4(acc[i][0], acc[i][1], acc[i][2], acc[i][3]);
    *(float4*)&X[(r0 + i) * LDST + c0] =
        make_float4(acc[i][0], acc[i][1], acc[i][2], acc[i][3]);
  }
  __syncthreads();
  size_t pbase = (size_t)m * FRAGM;
  for (int f = tid; f < 512; f += 256) {
    int l = f & 63, sl = (f >> 6) & 3, tt = (f >> 8) & 1;
    int tG = (gr0 >> 5) + tt, sG = slab * 4 + sl;
    int kl = sl * 16 + (l >> 5) * 8;
    size_t off = pbase + (((size_t)tG * 8 + sG) * 512 + (size_t)l * 8);
    frag_from_lds(X, tt * 32, kl, l, Ahi, Alo, off);
  }
}

// U12 64-col slab: U0 = invL00*T0 ; T1' = T1 - L10*U0 ; U1 = invL11*T1'; B-frags s=0..7
__device__ void u12_body(float* __restrict__ M, short* __restrict__ Bhi,
                         short* __restrict__ Blo, int k0, int bx, int m, int tid,
                         float* X, float* Y, float* Z, float* scr) {
  float* A = M + (size_t)m * NN * NN;
  int cg0 = k0 + 128 + bx * 64;
  int r0 = (tid >> 4) * 4, c0 = (tid & 15) * 4;
  size_t pbase = (size_t)m * FRAGM;
  float acc[4][4];
  load64(X, A, k0, k0, tid);
  __syncthreads();
  inv_lower64(X, Y, scr, tid);
  load64(X, A, k0, cg0, tid);          // T0
  __syncthreads();
  gemm64(Y, X, acc, r0, c0);           // U0
  __syncthreads();
#pragma unroll
  for (int i = 0; i < 4; ++i)
#pragma unroll
    for (int j = 0; j < 4; ++j) Z[(c0 + j) * LDST + r0 + i] = acc[i][j];  // Z = U0^T
  __syncthreads();
  for (int f = tid; f < 512; f += 256) {
    int l = f & 63, sl = (f >> 6) & 3, tt = (f >> 8) & 1;
    int tG = (cg0 >> 5) + tt;
    int kl = sl * 16 + (l >> 5) * 8;
    size_t off = pbase + (((size_t)tG * 8 + sl) * 512 + (size_t)l * 8);
    frag_from_lds(Z, tt * 32, kl, l, Bhi, Blo, off);
  }
  load64(X, A, k0 + 64, k0, tid);      // L10
  load64(Y, A, k0 + 64, cg0, tid);     // T1
  __syncthreads();
  gemm64_bt(X, Z, acc, r0, c0);        // L10*U0
#pragma unroll
  for (int i = 0; i < 4; ++i)
#pragma unroll
    for (int j = 0; j < 4; ++j) {
      float v = Y[(r0 + i) * LDST + c0 + j] - acc[i][j];
      Y[(r0 + i) * LDST + c0 + j] = v;     // own cells only
    }
  __syncthreads();
  load64(X, A, k0 + 64, k0 + 64, tid); // D1 (factored)
  __syncthreads();
  inv_lower64(X, Z, scr, tid);
  gemm64(Z, Y, acc, r0, c0);           // U1
  __syncthreads();
#pragma unroll
  for (int i = 0; i < 4; ++i)
#pragma unroll
    for (int j = 0; j < 4; ++j) X[(c0 + j) * LDST + r0 + i] = acc[i][j];  // X = U1^T
  __syncthreads();
  for (int f = tid; f < 512; f += 256) {
    int l = f & 63, sl = (f >> 6) & 3, tt = (f >> 8) & 1;
    int tG = (cg0 >> 5) + tt;
    int kl = sl * 16 + (l >> 5) * 8;
    size_t off = pbase + (((size_t)tG * 8 + 4 + sl) * 512 + (size_t)l * 8);
    frag_from_lds(X, tt * 32, kl, l, Bhi, Blo, off);
  }
}

__global__ __launch_bounds__(256) void ps0_kernel(float* __restrict__ M,
    short* __restrict__ Ahi, short* __restrict__ Alo, int k0) {
  __shared__ float lds[2 * 64 * LDST + 32 * 33];
  psolve_body(M, Ahi, Alo, k0, 0, blockIdx.x, blockIdx.y, threadIdx.x,
              lds, lds + 64 * LDST, lds + 2 * 64 * LDST);
}

__global__ __launch_bounds__(256) void step_mid(float* __restrict__ M,
    short* __restrict__ Ahi, short* __restrict__ Alo,
    short* __restrict__ Bhi, short* __restrict__ Blo, int k0) {
  __shared__ float lds[3 * 64 * LDST + 32 * 33];
  if (blockIdx.z == 0)
    psolve_body(M, Ahi, Alo, k0, 1, blockIdx.x, blockIdx.y, threadIdx.x,
                lds, lds + 64 * LDST, lds + 3 * 64 * LDST);
  else
    u12_body(M, Bhi, Blo, k0, blockIdx.x, blockIdx.y, threadIdx.x,
             lds, lds + 64 * LDST, lds + 2 * 64 * LDST, lds + 3 * 64 * LDST);
}

// first diagonal factor + U01 for step 0
__global__ __launch_bounds__(256) void fd_first(float* __restrict__ M,
    short* __restrict__ ibhi, short* __restrict__ iblo) {
  __shared__ float lds[2 * 64 * LDST + 32 * 33];
  float* X = lds; float* Y = lds + 64 * LDST; float* scr = lds + 2 * 64 * LDST;
  int m = blockIdx.x, tid = threadIdx.x;
  float* A = M + (size_t)m * NN * NN;
  load64(X, A, 0, 0, tid);
  __syncthreads();
  factor64(X, tid);
  store64(X, A, 0, 0, tid);
  inv_lower64(X, Y, scr, tid);
  load64(X, A, 0, 64, tid);
  __syncthreads();
  float acc[4][4]; int r0 = (tid >> 4) * 4, c0 = (tid & 15) * 4;
  gemm64(Y, X, acc, r0, c0);
  __syncthreads();
#pragma unroll
  for (int i = 0; i < 4; ++i)
#pragma unroll
    for (int j = 0; j < 4; ++j) X[(c0 + j) * LDST + r0 + i] = acc[i][j];
  __syncthreads();
  for (int f = tid; f < 512; f += 256) {
    int l = f & 63, sl = (f >> 6) & 3, tt = (f >> 8) & 1;
    int kl = sl * 16 + (l >> 5) * 8;
    size_t off = (((size_t)m * 2 + tt) * 4 + sl) * 512 + (size_t)l * 8;
    frag_from_lds(X, tt * 32, kl, l, ibhi, iblo, off);
  }
}

// inner 64-wide update (cols k0+64..k0+128), K=64 MFMA, fused factor of D1
__global__ __launch_bounds__(256) void ig_kernel(float* __restrict__ M,
    const short* __restrict__ Ahi, const short* __restrict__ Alo,
    const short* __restrict__ ibhi, const short* __restrict__ iblo, int k0) {
  __shared__ float X[64 * LDST];
  int m = blockIdx.y, tid = threadIdx.x;
  float* A = M + (size_t)m * NN * NN;
  int w = tid >> 6, l = tid & 63;
  int nr0 = (NN - k0 - 64) / 64;
  int T = blockIdx.x * 4 + w;
  if (T < nr0) {
    int gr0 = k0 + 64 + T * 64;
    size_t pbase = (size_t)m * FRAGM;
    int tA = gr0 >> 5;
    f32x16 acc[2][2];
#pragma unroll
    for (int i = 0; i < 2; ++i)
#pragma unroll
      for (int j = 0; j < 2; ++j)
#pragma unroll
        for (int q = 0; q < 16; ++q) acc[i][j][q] = 0.f;
#pragma unroll
    for (int s = 0; s < 4; ++s) {
      short8 ah[2], al[2], bh[2], bl[2];
#pragma unroll
      for (int t = 0; t < 2; ++t) {
        size_t oa = pbase + (((size_t)(tA + t) * 8 + s) * 512 + (size_t)l * 8);
        ah[t] = *(const short8*)(Ahi + oa);
        al[t] = *(const short8*)(Alo + oa);
        size_t ob = (((size_t)m * 2 + t) * 4 + s) * 512 + (size_t)l * 8;
        bh[t] = *(const short8*)(ibhi + ob);
        bl[t] = *(const short8*)(iblo + ob);
      }
#pragma unroll
      for (int i = 0; i < 2; ++i)
#pragma unroll
        for (int j = 0; j < 2; ++j) {
          acc[i][j] = __builtin_amdgcn_mfma_f32_32x32x16_bf16(ah[i], bh[j], acc[i][j], 0, 0, 0);
          acc[i][j] = __builtin_amdgcn_mfma_f32_32x32x16_bf16(ah[i], bl[j], acc[i][j], 0, 0, 0);
          acc[i][j] = __builtin_amdgcn_mfma_f32_32x32x16_bf16(al[i], bh[j], acc[i][j], 0, 0, 0);
        }
    }
    int lr = 4 * (l >> 5), lc = l & 31;
#pragma unroll
    for (int i = 0; i < 2; ++i)
#pragma unroll
      for (int j = 0; j < 2; ++j)
        rmw_tile(A, gr0 + i * 32 + lr, k0 + 64 + j * 32 + lc, acc[i][j]);
  }
  if (blockIdx.x == 0) {
    __syncthreads();
    load64(X, A, k0 + 64, k0 + 64, tid);
    __syncthreads();
    factor64(X, tid);
    store64(X, A, k0 + 64, k0 + 64, tid);
  }
}

// big trailing update, K=128 split-bf16 MFMA; fused next D0 factor + next U01
__global__ __launch_bounds__(256) void gemm2_kernel(float* __restrict__ M,
    const short* __restrict__ Ahi, const short* __restrict__ Alo,
    const short* __restrict__ Bhi, const short* __restrict__ Blo,
    short* __restrict__ ibhi, short* __restrict__ iblo, int k0) {
  __shared__ float lds[2 * 64 * LDST + 32 * 33];
  float* X = lds; float* Y = lds + 64 * LDST; float* scr = lds + 2 * 64 * LDST;
  int m = blockIdx.z, tid = threadIdx.x;
  float* A = M + (size_t)m * NN * NN;
  size_t pbase = (size_t)m * FRAGM;
  int w = tid >> 6, l = tid & 63, wr = w >> 1, wc = w & 1;
  int base = k0 + 128;
  int tb = base >> 5;
  int tr = tb + blockIdx.y * 4 + wr * 2;
  int tc = tb + blockIdx.x * 4 + wc * 2;
  f32x16 acc[2][2];
#pragma unroll
  for (int i = 0; i < 2; ++i)
#pragma unroll
    for (int j = 0; j < 2; ++j)
#pragma unroll
      for (int q = 0; q < 16; ++q) acc[i][j][q] = 0.f;
#pragma unroll
  for (int s = 0; s < 8; ++s) {
    short8 ah[2], al[2], bh[2], bl[2];
#pragma unroll
    for (int t = 0; t < 2; ++t) {
      size_t oa = pbase + (((size_t)(tr + t) * 8 + s) * 512 + (size_t)l * 8);
      ah[t] = *(const short8*)(Ahi + oa);
      al[t] = *(const short8*)(Alo + oa);
      size_t ob = pbase + (((size_t)(tc + t) * 8 + s) * 512 + (size_t)l * 8);
      bh[t] = *(const short8*)(Bhi + ob);
      bl[t] = *(const short8*)(Blo + ob);
    }
#pragma unroll
    for (int i = 0; i < 2; ++i)
#pragma unroll
      for (int j = 0; j < 2; ++j) {
        acc[i][j] = __builtin_amdgcn_mfma_f32_32x32x16_bf16(ah[i], bh[j], acc[i][j], 0, 0, 0);
        acc[i][j] = __builtin_amdgcn_mfma_f32_32x32x16_bf16(ah[i], bl[j], acc[i][j], 0, 0, 0);
        acc[i][j] = __builtin_amdgcn_mfma_f32_32x32x16_bf16(al[i], bh[j], acc[i][j], 0, 0, 0);
      }
  }
  int lr = 4 * (l >> 5), lc = l & 31;
#pragma unroll
  for (int i = 0; i < 2; ++i)
#pragma unroll
    for (int j = 0; j < 2; ++j)
      rmw_tile(A, (tr + i) * 32 + lr, (tc + j) * 32 + lc, acc[i][j]);
  if (blockIdx.x == 0 && blockIdx.y == 0) {
    __syncthreads();
    load64(X, A, base, base, tid);
    __syncthreads();
    factor64(X, tid);
    store64(X, A, base, base, tid);
    inv_lower64(X, Y, scr, tid);
    load64(X, A, base, base + 64, tid);
    __syncthreads();
    float a4[4][4]; int r0 = (tid >> 4) * 4, c0 = (tid & 15) * 4;
    gemm64(Y, X, a4, r0, c0);
    __syncthreads();
#pragma unroll
    for (int i = 0; i < 4; ++i)
#pragma unroll
      for (int j = 0; j < 4; ++j) X[(c0 + j) * LDST + r0 + i] = a4[i][j];
    __syncthreads();
    for (int f = tid; f < 512; f += 256) {
      int ll = f & 63, sl = (f >> 6) & 3, tt = (f >> 8) & 1;
      int kl = sl * 16 + (ll >> 5) * 8;
      size_t off = (((size_t)m * 2 + tt) * 4 + sl) * 512 + (size_t)ll * 8;
      frag_from_lds(X, tt * 32, kl, ll, ibhi, iblo, off);
    }
  }
}

// ---------------- reduction ----------------

__global__ void logdet_kernel(const float* __restrict__ Mb, double* __restrict__ dlog) {
  int m = blockIdx.x;
  const float* A = Mb + (size_t)m * NN * NN;
  double s = 0.0;
  for (int i = threadIdx.x; i < NN; i += 256)
    s += (double)logf(fabsf(A[(size_t)i * NN + i]));
  __shared__ double red[256];
  red[threadIdx.x] = s;
  __syncthreads();
  for (int k = 128; k > 0; k >>= 1) {
    if (threadIdx.x < k) red[threadIdx.x] += red[threadIdx.x + k];
    __syncthreads();
  }
  if (threadIdx.x == 0) dlog[m] = red[0];
}

__global__ void final_kernel(const double* __restrict__ dlog, float* __restrict__ out) {
  if (threadIdx.x == 0) {
    double acc = 0.0;
    for (int b = 0; b < NBATCH; ++b) acc += dlog[b] - dlog[NBATCH + b];
    out[0] = (float)(acc * 0.25);
  }
}

// ---------------- launch ----------------

extern "C" void kernel_launch(void* const* d_in, const int* in_sizes, int n_in,
                              void* d_out, int out_size, void* d_ws, size_t ws_size,
                              hipStream_t stream) {
  const float* scores  = (const float*)d_in[0];
  const float* tm      = (const float*)d_in[1];
  const float* zm      = (const float*)d_in[2];
  const int*   lengths = (const int*)d_in[3];
  float* out = (float*)d_out;

  char* p = (char*)d_ws;
  float* M = (float*)p;      p += (size_t)NMAT * NN * NN * sizeof(float);
  short* Ahi = (short*)p;    p += NMAT * FRAGM * sizeof(short);
  short* Alo = (short*)p;    p += NMAT * FRAGM * sizeof(short);
  short* Bhi = (short*)p;    p += NMAT * FRAGM * sizeof(short);
  short* Blo = (short*)p;    p += NMAT * FRAGM * sizeof(short);
  short* ibhi = (short*)p;   p += (size_t)NMAT * 2 * 4 * 512 * sizeof(short);
  short* iblo = (short*)p;   p += (size_t)NMAT * 2 * 4 * 512 * sizeof(short);
  float* cs = (float*)p;     p += (size_t)NMAT * NN * sizeof(float);
  double* dlog = (double*)p;

  init_cs_kernel<<<(NMAT * NN + 255) / 256, 256, 0, stream>>>(cs);
  build_kernel<<<dim3((NN + 255) / 256, NN / 16, NBATCH), 256, 0, stream>>>(
      scores, zm, tm, lengths, M, cs);
  diag_fix_kernel<<<dim3((NN + 255) / 256, NMAT), 256, 0, stream>>>(
      scores, zm, tm, lengths, cs, M);
  fd_first<<<NMAT, 256, 0, stream>>>(M, ibhi, iblo);

  for (int k0 = 0; k0 < NN - 64; k0 += 128) {
    int rem2 = NN - k0 - 128;
    int nr0 = (NN - k0 - 64) / 64;
    ps0_kernel<<<dim3(nr0, NMAT), 256, 0, stream>>>(M, Ahi, Alo, k0);
    ig_kernel<<<dim3((nr0 + 3) / 4, NMAT), 256, 0, stream>>>(M, Ahi, Alo, ibhi, iblo, k0);
    if (rem2 > 0) {
      step_mid<<<dim3(rem2 / 64, NMAT, 2), 256, 0, stream>>>(M, Ahi, Alo, Bhi, Blo, k0);
      gemm2_kernel<<<dim3(rem2 / 128, rem2 / 128, NMAT), 256, 0, stream>>>(
          M, Ahi, Alo, Bhi, Blo, ibhi, iblo, k0);
    }
  }

  logdet_kernel<<<NMAT, 256, 0, stream>>>(M, dlog);
  final_kernel<<<1, 64, 0, stream>>>(dlog, out);
}